// Round 2
// baseline (288.781 us; speedup 1.0000x reference)
//
#include <hip/hip_runtime.h>

// RoPEAttentionHead: x[256,16,2048], w_q/w_k/w_v [2048,2048] -> out [256,16,2048]
// Input dtype (f32 vs bf16) detected at runtime from bit patterns; all compute in bf16 MFMA.
// Stage 0: (f32 only) convert inputs -> bf16 in ws
// Stage 1: fused QKV GEMM (C = X @ W^T) + rotary epilogue -> ws (bf16 q_rot, k_rot, v)
// Stage 2: per-batch 16x16 attention (MFMA scores, shuffle softmax, VALU PV)

#define D 2048
#define SEQLEN 16
#define NBATCH 256
#define NROWS (NBATCH * SEQLEN)   // 4096
#define NX (NROWS * D)            // 8388608 elements in x (and in each of q,k,v,out)
#define NW (D * D)                // 4194304 elements per weight

typedef __attribute__((ext_vector_type(8))) short bf16x8;   // 8 bf16 = 4 VGPRs
typedef __attribute__((ext_vector_type(4))) float f32x4;

__device__ __forceinline__ unsigned short f32_to_bf16(float f) {
  unsigned u = __float_as_uint(f);
  unsigned r = 0x7fffu + ((u >> 16) & 1u);   // RNE
  return (unsigned short)((u + r) >> 16);
}
__device__ __forceinline__ float bf16lo_to_f32(unsigned u) { return __uint_as_float(u << 16); }
__device__ __forceinline__ float bf16hi_to_f32(unsigned u) { return __uint_as_float(u & 0xffff0000u); }

// True if `w` holds float32 data (reading it as bf16 gives wild exponents).
// Uniform across all threads: everyone reads the same 64 ushorts (cached).
__device__ __forceinline__ bool detect_f32(const ushort* __restrict__ w) {
  int crazy = 0;
#pragma unroll
  for (int i = 0; i < 64; ++i) {
    float v = __uint_as_float((unsigned)w[i] << 16);
    if (!(__builtin_fabsf(v) < 256.0f)) ++crazy;   // catches huge AND NaN
  }
  return crazy >= 3;
}

__device__ __forceinline__ void glds16(const void* g, void* l) {
  __builtin_amdgcn_global_load_lds(
      (const __attribute__((address_space(1))) void*)g,
      (__attribute__((address_space(3))) void*)l, 16, 0, 0);
}

// ---------------- Stage 0: f32 -> bf16 conversion (no-op for bf16 inputs) ----------------
__global__ __launch_bounds__(256) void convert_inputs(
    const void* __restrict__ x, const void* __restrict__ wq,
    const void* __restrict__ wk, const void* __restrict__ wv,
    ushort* __restrict__ xb, ushort* __restrict__ wqb,
    ushort* __restrict__ wkb, ushort* __restrict__ wvb) {
  if (!detect_f32((const ushort*)wq)) return;
  const float* srcs[4] = {(const float*)x, (const float*)wq, (const float*)wk, (const float*)wv};
  ushort* dsts[4] = {xb, wqb, wkb, wvb};
  const int ns[4] = {NX, NW, NW, NW};
  const int stride = gridDim.x * blockDim.x;
#pragma unroll
  for (int s = 0; s < 4; ++s) {
    const float* __restrict__ src = srcs[s];
    ushort* __restrict__ dst = dsts[s];
    const int n8 = ns[s] / 8;
    for (int i = blockIdx.x * blockDim.x + threadIdx.x; i < n8; i += stride) {
      float4 a = ((const float4*)src)[i * 2];
      float4 b = ((const float4*)src)[i * 2 + 1];
      uint4 o;
      o.x = (unsigned)f32_to_bf16(a.x) | ((unsigned)f32_to_bf16(a.y) << 16);
      o.y = (unsigned)f32_to_bf16(a.z) | ((unsigned)f32_to_bf16(a.w) << 16);
      o.z = (unsigned)f32_to_bf16(b.x) | ((unsigned)f32_to_bf16(b.y) << 16);
      o.w = (unsigned)f32_to_bf16(b.z) | ((unsigned)f32_to_bf16(b.w) << 16);
      ((uint4*)dst)[i] = o;
    }
  }
}

// ---------------- Stage 1: QKV GEMM + rotary ----------------
// grid (M/128=32, N/128=16, 3), block 256 (4 waves, 2x2; each wave 64x64 = 4x4 MFMA tiles)
__global__ __launch_bounds__(256) void qkv_rope_gemm(
    const void* __restrict__ Xr, const void* __restrict__ Wqr,
    const void* __restrict__ Wkr, const void* __restrict__ Wvr,
    const ushort* __restrict__ xb, const ushort* __restrict__ wqb,
    const ushort* __restrict__ wkb, const ushort* __restrict__ wvb,
    ushort* __restrict__ Oq, ushort* __restrict__ Ok, ushort* __restrict__ Ov) {
  __shared__ __align__(16) ushort As[128 * 32];
  __shared__ __align__(16) ushort Bs[128 * 32];

  const bool f32in = detect_f32((const ushort*)Wqr);
  const ushort* __restrict__ X = f32in ? xb : (const ushort*)Xr;
  const int z = blockIdx.z;
  const ushort* __restrict__ W =
      (z == 0) ? (f32in ? wqb : (const ushort*)Wqr)
               : (z == 1) ? (f32in ? wkb : (const ushort*)Wkr)
                          : (f32in ? wvb : (const ushort*)Wvr);
  ushort* __restrict__ O = (z == 0) ? Oq : (z == 1) ? Ok : Ov;

  const int m0 = blockIdx.x * 128;
  const int n0 = blockIdx.y * 128;
  const int t = threadIdx.x;
  const int wave = t >> 6;
  const int lane = t & 63;
  const int quad = lane >> 4;
  const int l16 = lane & 15;
  const int wm = (wave >> 1) * 64;
  const int wn = (wave & 1) * 64;

  // global_load_lds staging: per wave 2 chunks of 16 rows x 32 cols (1024B each),
  // LDS dest = wave-uniform base + lane*16B (required pattern; no padding allowed)
  const int srow = wave * 32 + (lane >> 2);
  const int scol = (lane & 3) * 8;
  const ushort* gA = X + (size_t)(m0 + srow) * D + scol;
  const ushort* gB = W + (size_t)(n0 + srow) * D + scol;
  ushort* lA = As + wave * 1024 + lane * 8;   // bytes: wave*2048 + lane*16
  ushort* lB = Bs + wave * 1024 + lane * 8;

  f32x4 acc[4][4] = {};

  for (int k0 = 0; k0 < D; k0 += 32) {
    glds16(gA + k0, lA);
    glds16(gA + 16 * D + k0, lA + 512);
    glds16(gB + k0, lB);
    glds16(gB + 16 * D + k0, lB + 512);
    __syncthreads();   // compiler emits vmcnt(0) drain -> LDS tiles complete

    bf16x8 af[4], bfr[4];
#pragma unroll
    for (int i = 0; i < 4; ++i) {
      af[i]  = *(const bf16x8*)(As + (wm + i * 16 + l16) * 32 + quad * 8);
      bfr[i] = *(const bf16x8*)(Bs + (wn + i * 16 + l16) * 32 + quad * 8);
    }
#pragma unroll
    for (int i = 0; i < 4; ++i)
#pragma unroll
      for (int j = 0; j < 4; ++j)
        acc[i][j] = __builtin_amdgcn_mfma_f32_16x16x32_bf16(af[i], bfr[j], acc[i][j], 0, 0, 0);
    __syncthreads();
  }

  // Epilogue: rotary (z<2) + bf16 store.
  // C layout: col = lane&15 (e), row = quad*4+reg (m mod 16 since all tile offsets are x16).
  // Pair (2i, 2i+1) along e differs only in bit0 of l16 -> partner = shfl_xor(v, 1).
  const bool rope = (z != 2);
#pragma unroll
  for (int j = 0; j < 4; ++j) {
    const int e = n0 + wn + j * 16 + l16;
    float cs[4], sn[4];
    if (rope) {
      // theta = 10000^(-2*(i-1)/2048), i = e>>1  (keeps the reference's i-1 "bug")
      const float theta = exp2f(-0.012976281620653759f * ((float)(e >> 1) - 1.0f));
#pragma unroll
      for (int r = 0; r < 4; ++r)
        __sincosf((float)(quad * 4 + r) * theta, &sn[r], &cs[r]);
    }
#pragma unroll
    for (int i = 0; i < 4; ++i) {
#pragma unroll
      for (int r = 0; r < 4; ++r) {
        float v = acc[i][j][r];
        float p = __shfl_xor(v, 1);
        float o;
        if (rope)
          o = (e & 1) ? (v * cs[r] - p * sn[r])    // odd:  -q[2i]*sin + q[2i+1]*cos
                      : (v * cs[r] + p * sn[r]);   // even:  q[2i]*cos + q[2i+1]*sin
        else
          o = v;
        O[(size_t)(m0 + wm + i * 16 + quad * 4 + r) * D + e] = f32_to_bf16(o);
      }
    }
  }
}

// ---------------- Stage 2: attention ----------------
// grid 256 (one block per batch), block 256.
// scores[16][16] = q_rot @ k_rot^T via 16x16x32 MFMA, K=2048 split 4 ways across waves.
__global__ __launch_bounds__(256) void rope_attention(
    const ushort* __restrict__ Q, const ushort* __restrict__ K,
    const ushort* __restrict__ V, const void* __restrict__ Wqr, void* __restrict__ OutRaw) {
  __shared__ float sc[4][16][16];
  __shared__ float at[16][16];
  const bool f32out = detect_f32((const ushort*)Wqr);
  const int b = blockIdx.x;
  const int t = threadIdx.x;
  const int wave = t >> 6, lane = t & 63;
  const int quad = lane >> 4, l16 = lane & 15;

  const ushort* Qb = Q + (size_t)b * (SEQLEN * D);
  const ushort* Kb = K + (size_t)b * (SEQLEN * D);

  f32x4 acc = {0.f, 0.f, 0.f, 0.f};
  const ushort* qp = Qb + l16 * D + wave * 512 + quad * 8;
  const ushort* kp = Kb + l16 * D + wave * 512 + quad * 8;
#pragma unroll
  for (int s = 0; s < 16; ++s) {
    bf16x8 a = *(const bf16x8*)(qp + s * 32);
    bf16x8 bb = *(const bf16x8*)(kp + s * 32);
    acc = __builtin_amdgcn_mfma_f32_16x16x32_bf16(a, bb, acc, 0, 0, 0);
  }
#pragma unroll
  for (int r = 0; r < 4; ++r)
    sc[wave][quad * 4 + r][l16] = acc[r];
  __syncthreads();

  {
    const int m = t >> 4, n = t & 15;
    float s = (sc[0][m][n] + sc[1][m][n] + sc[2][m][n] + sc[3][m][n]) * 0.02209708691207961f;
    float mx = s;
#pragma unroll
    for (int off = 8; off; off >>= 1) mx = fmaxf(mx, __shfl_xor(mx, off, 16));
    float e = __expf(s - mx);
    float sum = e;
#pragma unroll
    for (int off = 8; off; off >>= 1) sum += __shfl_xor(sum, off, 16);
    at[m][n] = e / sum;
  }
  __syncthreads();

  // PV: thread t owns 8 contiguous e-cols; v held in regs as packed bf16 (16 rows x 16B).
  const ushort* Vb = V + (size_t)b * (SEQLEN * D);
  const int e0 = t * 8;
  uint4 vr[16];
#pragma unroll
  for (int n = 0; n < 16; ++n)
    vr[n] = *(const uint4*)(Vb + n * D + e0);

  for (int m = 0; m < 16; ++m) {
    float av[8] = {0.f, 0.f, 0.f, 0.f, 0.f, 0.f, 0.f, 0.f};
#pragma unroll
    for (int n = 0; n < 16; ++n) {
      const float a = at[m][n];
      const uint4 u = vr[n];
      av[0] = fmaf(a, bf16lo_to_f32(u.x), av[0]);
      av[1] = fmaf(a, bf16hi_to_f32(u.x), av[1]);
      av[2] = fmaf(a, bf16lo_to_f32(u.y), av[2]);
      av[3] = fmaf(a, bf16hi_to_f32(u.y), av[3]);
      av[4] = fmaf(a, bf16lo_to_f32(u.z), av[4]);
      av[5] = fmaf(a, bf16hi_to_f32(u.z), av[5]);
      av[6] = fmaf(a, bf16lo_to_f32(u.w), av[6]);
      av[7] = fmaf(a, bf16hi_to_f32(u.w), av[7]);
    }
    if (f32out) {
      float* Ob = (float*)OutRaw + (size_t)b * (SEQLEN * D) + m * D + e0;
      float4 o0 = {av[0], av[1], av[2], av[3]};
      float4 o1 = {av[4], av[5], av[6], av[7]};
      ((float4*)Ob)[0] = o0;
      ((float4*)Ob)[1] = o1;
    } else {
      uint4 o;
      o.x = (unsigned)f32_to_bf16(av[0]) | ((unsigned)f32_to_bf16(av[1]) << 16);
      o.y = (unsigned)f32_to_bf16(av[2]) | ((unsigned)f32_to_bf16(av[3]) << 16);
      o.z = (unsigned)f32_to_bf16(av[4]) | ((unsigned)f32_to_bf16(av[5]) << 16);
      o.w = (unsigned)f32_to_bf16(av[6]) | ((unsigned)f32_to_bf16(av[7]) << 16);
      *(uint4*)((ushort*)OutRaw + (size_t)b * (SEQLEN * D) + m * D + e0) = o;
    }
  }
}

extern "C" void kernel_launch(void* const* d_in, const int* in_sizes, int n_in,
                              void* d_out, int out_size, void* d_ws, size_t ws_size,
                              hipStream_t stream) {
  const void* x  = d_in[0];
  const void* wq = d_in[1];
  const void* wk = d_in[2];
  const void* wv = d_in[3];
  ushort* ws = (ushort*)d_ws;
  // ws layout (ushort units): converted inputs then q,k,v  (total 92.3 MB)
  ushort* xb  = ws;
  ushort* wqb = ws + NX;
  ushort* wkb = ws + NX + NW;
  ushort* wvb = ws + NX + 2 * (size_t)NW;
  ushort* q = ws + NX + 3 * (size_t)NW;
  ushort* k = q + NX;
  ushort* v = k + NX;

  convert_inputs<<<512, 256, 0, stream>>>(x, wq, wk, wv, xb, wqb, wkb, wvb);
  qkv_rope_gemm<<<dim3(32, 16, 3), 256, 0, stream>>>(x, wq, wk, wv, xb, wqb, wkb, wvb, q, k, v);
  rope_attention<<<NBATCH, 256, 0, stream>>>(q, k, v, wq, (ushort*)d_out);
}